// Round 11
// baseline (131.325 us; speedup 1.0000x reference)
//
#include <hip/hip_runtime.h>
#include <hip/hip_bf16.h>

#define B_    8
#define CIN   256
#define COUT  768
#define G_    24
#define PW    40         // padded row width (16B-aligned rows)
#define PLANE 1440       // 40*36
#define EPS_  1e-5f

typedef float f32x4 __attribute__((ext_vector_type(4)));
typedef short s16x8 __attribute__((ext_vector_type(8)));
typedef unsigned short ushort_t;
typedef unsigned short u16x4 __attribute__((ext_vector_type(4)));
typedef unsigned long long ull_t;

// LDS-only fence: compiler reordering barrier + s_waitcnt lgkmcnt(0).
// Does NOT wait vmcnt -> global prefetch loads stay in flight.
#define LDS_FENCE() do { asm volatile("" ::: "memory"); \
                         __builtin_amdgcn_s_waitcnt(0xC07F); \
                         asm volatile("" ::: "memory"); } while (0)

static __device__ __forceinline__ ushort_t f2bf(float f) {
    union { float f; unsigned u; } a; a.f = f;
    const unsigned u = a.u;
    const unsigned r = u + 0x7FFFu + ((u >> 16) & 1u);
    return (ushort_t)(r >> 16);
}
static __device__ __forceinline__ float bf2f(ushort_t h) {
    union { unsigned u; float f; } a; a.u = ((unsigned)h) << 16; return a.f;
}
static __device__ __forceinline__ void st4(float* dst, u16x4 v) {
    *(f32x4*)dst = f32x4{ bf2f(v[0]), bf2f(v[1]), bf2f(v[2]), bf2f(v[3]) };
}
static __device__ __forceinline__ unsigned pk2(float lo, float hi) {
    return (unsigned)f2bf(lo) | ((unsigned)f2bf(hi) << 16);
}

// ---------------- Kernel 1: fused prep + bf16 MFMA GEMM -> attn + rowAgg -----
__launch_bounds__(256)
__global__ void conv_gemm(const float* __restrict__ wsrc, const float* __restrict__ x,
                          const float* __restrict__ bias, ushort_t* __restrict__ attn,
                          float* __restrict__ rowAgg) {
    const int t = threadIdx.x;
    const int wv = t >> 6, lane = t & 63;
    const int q = lane >> 4, l15 = lane & 15;
    const int m0 = blockIdx.y * 64;
    const int mw = wv * 16;
    const int n_t = blockIdx.x * 64;
    const int b = n_t >> 10, nl0 = n_t & 1023;
    const int y0 = nl0 >> 5;

    __shared__ ushort_t Bs[64][264];     // [n][k] bf16, row stride 264 hw (33792 B)
    ushort_t (*Ct)[2][44] = (ushort_t (*)[2][44])(&Bs[0][0]);
    float (*red)[11]      = (float (*)[11])((char*)(&Bs[0][0]) + 64 * 2 * 44 * 2);

    // ---- stage B: x[b][k][nl0..nl0+63] fp32 -> Bs[n][k] bf16 (transpose+cvt)
    {
        const int half = t >> 7;
        const int kp = t & 127;
        const int k2 = kp * 2;
        const float* xr0 = x + (size_t)b * (CIN * 1024) + (size_t)k2 * 1024 + nl0 + half * 32;
        const float* xr1 = xr0 + 1024;
        #pragma unroll
        for (int c = 0; c < 8; ++c) {
            const float4 u0 = *(const float4*)(xr0 + c * 4);
            const float4 u1 = *(const float4*)(xr1 + c * 4);
            const int nn = half * 32 + c * 4;
            *(unsigned*)&Bs[nn + 0][k2] = pk2(u0.x, u1.x);
            *(unsigned*)&Bs[nn + 1][k2] = pk2(u0.y, u1.y);
            *(unsigned*)&Bs[nn + 2][k2] = pk2(u0.z, u1.z);
            *(unsigned*)&Bs[nn + 3][k2] = pk2(u0.w, u1.w);
        }
    }
    __syncthreads();

    const float* aPf = wsrc + (size_t)(m0 + mw + l15) * 256 + q * 8;

    f32x4 acc[4] = {{0,0,0,0},{0,0,0,0},{0,0,0,0},{0,0,0,0}};
    #pragma unroll
    for (int k0 = 0; k0 < 256; k0 += 32) {
        const float4 af0 = *(const float4*)(aPf + k0);
        const float4 af1 = *(const float4*)(aPf + k0 + 4);
        s16x8 a;
        a[0] = (short)f2bf(af0.x); a[1] = (short)f2bf(af0.y);
        a[2] = (short)f2bf(af0.z); a[3] = (short)f2bf(af0.w);
        a[4] = (short)f2bf(af1.x); a[5] = (short)f2bf(af1.y);
        a[6] = (short)f2bf(af1.z); a[7] = (short)f2bf(af1.w);
        const int kk = k0 + q * 8;
        const s16x8 b0 = *(const s16x8*)&Bs[l15 +  0][kk];
        const s16x8 b1 = *(const s16x8*)&Bs[l15 + 16][kk];
        const s16x8 b2 = *(const s16x8*)&Bs[l15 + 32][kk];
        const s16x8 b3 = *(const s16x8*)&Bs[l15 + 48][kk];
        acc[0] = __builtin_amdgcn_mfma_f32_16x16x32_bf16(a, b0, acc[0], 0, 0, 0);
        acc[1] = __builtin_amdgcn_mfma_f32_16x16x32_bf16(a, b1, acc[1], 0, 0, 0);
        acc[2] = __builtin_amdgcn_mfma_f32_16x16x32_bf16(a, b2, acc[2], 0, 0, 0);
        acc[3] = __builtin_amdgcn_mfma_f32_16x16x32_bf16(a, b3, acc[3], 0, 0, 0);
    }
    __syncthreads();   // Bs dead; Ct/red aliasing begins

    float bb[4];
    #pragma unroll
    for (int r = 0; r < 4; ++r) bb[r] = bias[m0 + mw + q * 4 + r];
    #pragma unroll
    for (int j = 0; j < 4; ++j) {
        const int yy = j >> 1, xx = (j & 1) * 16 + l15;
        #pragma unroll
        for (int r = 0; r < 4; ++r)
            Ct[mw + q * 4 + r][yy][2 + xx] = f2bf(acc[j][r] + bb[r]);
    }
    #pragma unroll
    for (int it = 0; it < 2; ++it) {
        const int id = it * 256 + t;
        const int m = id >> 3, yy = (id >> 2) & 1, pos = id & 3;
        const int us = (pos == 0) ? 0 : (32 + 2 * pos);
        *(unsigned*)&Ct[m][yy][us] = 0u;
    }
    __syncthreads();

    ushort_t* pb = attn + ((size_t)(b * COUT + m0)) * PLANE;
    #pragma unroll
    for (int it = 0; it < 5; ++it) {
        const int id = it * 256 + t;
        const int m = id / 20, rem = id % 20, yy = rem / 10, s = rem % 10;
        const ull_t v = *(const ull_t*)&Ct[m][yy][s * 4];
        *(ull_t*)(pb + (size_t)m * PLANE + (y0 + yy + 2) * PW + s * 4) = v;
    }
    if (y0 == 0 || y0 == 30) {
        const int rowA = (y0 == 0) ? 0 : 34;
        #pragma unroll
        for (int it = 0; it < 5; ++it) {
            const int id = it * 256 + t;
            const int m = id / 20, rem = id % 20, yy = rem / 10, s = rem % 10;
            *(ull_t*)(pb + (size_t)m * PLANE + (rowA + yy) * PW + s * 4) = 0ull;
        }
    }

    if (t < 128) {
        const int gi = t >> 6, yy = (t >> 5) & 1, c = t & 31;
        const int m = gi * 32 + c;
        float lin = 0.f, sq = 0.f, e0 = 0.f, e1 = 0.f, e30 = 0.f, e31 = 0.f;
        #pragma unroll
        for (int u = 0; u < 9; ++u) {
            const ull_t vv = *(const ull_t*)&Ct[m][yy][u * 4];
            const unsigned lo = (unsigned)vv, hi = (unsigned)(vv >> 32);
            union { unsigned u; float f; } f0, f1, f2, f3;
            f0.u = lo << 16; f1.u = lo & 0xffff0000u;
            f2.u = hi << 16; f3.u = hi & 0xffff0000u;
            lin += (f0.f + f1.f) + (f2.f + f3.f);
            sq  += (f0.f * f0.f + f1.f * f1.f) + (f2.f * f2.f + f3.f * f3.f);
            if (u == 0) { e0 = f2.f; e1 = f3.f; }
            if (u == 8) { e30 = f0.f; e31 = f1.f; }
        }
        red[t][0] = lin; red[t][1] = sq;
        red[t][2] = e0;  red[t][3] = e0 * e0;
        red[t][4] = e1;  red[t][5] = e1 * e1;
        red[t][6] = e30; red[t][7] = e30 * e30;
        red[t][8] = e31; red[t][9] = e31 * e31;
    }
    __syncthreads();
    if (t < 40) {
        const int s = t % 10, gy = t / 10;
        const int gi = gy >> 1, yy = gy & 1;
        float sum = 0.f;
        #pragma unroll
        for (int c = 0; c < 32; ++c) sum += red[gi * 64 + yy * 32 + c][s];
        const int g = blockIdx.y * 2 + gi;
        rowAgg[(((size_t)b * G_ + g) * 32 + (y0 + yy)) * 10 + s] = sum;
    }
}

// ---------------- Kernel 2: local attention — 1-wave blocks, fused GN-stats
// finalize (from rowAgg), intra-wave channel split, double-buffered LDS,
// fence-only pipeline, XCD-swizzled block mapping ----------------------------
__launch_bounds__(64)
__global__ void local_attn(const ushort_t* __restrict__ attn,
                           const float* __restrict__ rowAgg,
                           const float* __restrict__ gn_w, const float* __restrict__ gn_b,
                           float* __restrict__ out) {
    // XCD swizzle: consecutive blockIdx round-robin across 8 XCDs; give each
    // XCD a contiguous span of 256 work-ids (= one full batch -> L2-resident).
    const int blk = blockIdx.x;          // 2048
    const int wid = (blk >> 3) | ((blk & 7) << 8);
    const int b = wid >> 8;
    const int n = (wid >> 5) & 7;
    const int i0 = wid & 31;             // image row
    const int t = threadIdx.x;           // 64
    const int h = t >> 5;                // channel half
    const int j = t & 31;                // pixel column

    __shared__ float KB[2][2][208];      // [half][buf][5 rows x 40 + pad]
    __shared__ float QB[2][2][208];
    __shared__ float rpL[96][5], rp2L[96][5];   // per (gi*32+y) window col-sums
    __shared__ float s_m[75], s_r[75];          // per (gi*25+p) mean / rstd
    __shared__ float s_rq[25], s_mq[25], s_rk[25], s_ck[25], s_rv[25], s_cv[25];
    __shared__ float s_gw[96], s_gb[96];

    s_gw[t] = gn_w[n * 96 + t];
    s_gb[t] = gn_b[n * 96 + t];
    if (t < 32) {
        s_gw[64 + t] = gn_w[n * 96 + 64 + t];
        s_gb[64 + t] = gn_b[n * 96 + 64 + t];
    }

    // ---- fused gnfin, phase 1: per-(group,row) window column sums ----------
    const float* rab = rowAgg + (size_t)((b * G_ + n * 3) * 32) * 10;
    #pragma unroll
    for (int pass = 0; pass < 2; ++pass) {
        const int e = (pass == 0) ? t : 64 + t;   // e = gi*32 + y, 96 tasks
        if (pass == 0 || t < 32) {
            const float* a = rab + (size_t)e * 10;
            const float S = a[0], Sq = a[1];
            const float e0 = a[2], q0 = a[3], e1 = a[4], q1 = a[5];
            const float e30 = a[6], q30 = a[7], e31 = a[8], q31 = a[9];
            rpL[e][0] = S - e30 - e31; rpL[e][1] = S - e31; rpL[e][2] = S;
            rpL[e][3] = S - e0;        rpL[e][4] = S - e0 - e1;
            rp2L[e][0] = Sq - q30 - q31; rp2L[e][1] = Sq - q31; rp2L[e][2] = Sq;
            rp2L[e][3] = Sq - q0;        rp2L[e][4] = Sq - q0 - q1;
        }
    }
    __syncthreads();

    // ---- fused gnfin, phase 2: 75 (group,window) mean/rstd entries ---------
    #pragma unroll
    for (int pass = 0; pass < 2; ++pass) {
        const int e = (pass == 0) ? t : 64 + t;
        if (e < 75) {
            const int gi = e / 25, p = e % 25;
            const int kw = p % 5, kh = p / 5;
            const int rb = gi * 32;
            float cs = 0.f, cs2 = 0.f;
            #pragma unroll
            for (int yy = 0; yy < 32; ++yy) { cs += rpL[rb + yy][kw]; cs2 += rp2L[rb + yy][kw]; }
            if (kh == 0)      { cs -= rpL[rb + 30][kw] + rpL[rb + 31][kw]; cs2 -= rp2L[rb + 30][kw] + rp2L[rb + 31][kw]; }
            else if (kh == 1) { cs -= rpL[rb + 31][kw];                    cs2 -= rp2L[rb + 31][kw]; }
            else if (kh == 3) { cs -= rpL[rb + 0][kw];                     cs2 -= rp2L[rb + 0][kw]; }
            else if (kh == 4) { cs -= rpL[rb + 0][kw] + rpL[rb + 1][kw];   cs2 -= rp2L[rb + 0][kw] + rp2L[rb + 1][kw]; }
            const float inv_n = 1.f / 32768.f;
            const float mean = cs * inv_n;
            const float var  = cs2 * inv_n - mean * mean;
            s_m[e] = mean;
            s_r[e] = rsqrtf(var + EPS_);
        }
    }
    __syncthreads();

    if (t < 25) {
        const float mK = s_m[t],      rK = s_r[t];
        const float mQ = s_m[25 + t], rQ = s_r[25 + t];
        const float mV = s_m[50 + t], rV = s_r[50 + t];
        s_rk[t] = rK; s_ck[t] = mK * rK;
        s_rq[t] = rQ; s_mq[t] = mQ * rQ;
        s_rv[t] = rV; s_cv[t] = mV * rV;
    }
    __syncthreads();

    float rq[25]; float cQ = 0.f;
    #pragma unroll
    for (int p = 0; p < 25; ++p) { rq[p] = s_rq[p]; cQ += s_mq[p]; }

    const ushort_t* regB = attn + (size_t)(b * COUT + n * 96) * PLANE + i0 * PW;
    const bool stg = (j < 25);
    const int eo1 = j * 4, eo2 = (j + 25) * 4;

    const ushort_t* baseK = regB + (size_t)(h * 16) * PLANE;
    const ushort_t* baseQ = regB + (size_t)(32 + h * 16) * PLANE;
    const ushort_t* baseV = regB + (size_t)(64 + h * 16) * PLANE;

    u16x4 nK1{0,0,0,0}, nK2{0,0,0,0}, nQ1{0,0,0,0}, nQ2{0,0,0,0};
    u16x4 fK1{0,0,0,0}, fK2{0,0,0,0}, fQ1{0,0,0,0}, fQ2{0,0,0,0};
    if (stg) {
        const u16x4 a1 = *(const u16x4*)(baseK + eo1), a2 = *(const u16x4*)(baseK + eo2);
        const u16x4 q1 = *(const u16x4*)(baseQ + eo1), q2 = *(const u16x4*)(baseQ + eo2);
        st4(&KB[h][0][eo1], a1); st4(&KB[h][0][eo2], a2);
        st4(&QB[h][0][eo1], q1); st4(&QB[h][0][eo2], q2);
        nK1 = *(const u16x4*)(baseK + PLANE + eo1); nK2 = *(const u16x4*)(baseK + PLANE + eo2);
        nQ1 = *(const u16x4*)(baseQ + PLANE + eo1); nQ2 = *(const u16x4*)(baseQ + PLANE + eo2);
        fK1 = *(const u16x4*)(baseK + 2 * (size_t)PLANE + eo1);
        fK2 = *(const u16x4*)(baseK + 2 * (size_t)PLANE + eo2);
        fQ1 = *(const u16x4*)(baseQ + 2 * (size_t)PLANE + eo1);
        fQ2 = *(const u16x4*)(baseQ + 2 * (size_t)PLANE + eo2);
    }
    LDS_FENCE();

    float sal[25];
    #pragma unroll
    for (int p = 0; p < 25; ++p) sal[p] = 0.f;
    float sumQ2 = 0.f, sumQB = 0.f;

    for (int cc = 0; cc < 16; ++cc) {
        const int buf = cc & 1;
        if (stg && cc < 15) {
            st4(&KB[h][buf ^ 1][eo1], nK1); st4(&KB[h][buf ^ 1][eo2], nK2);
            st4(&QB[h][buf ^ 1][eo1], nQ1); st4(&QB[h][buf ^ 1][eo2], nQ2);
            nK1 = fK1; nK2 = fK2; nQ1 = fQ1; nQ2 = fQ2;
            if (cc < 13) {
                fK1 = *(const u16x4*)(baseK + (size_t)(cc + 3) * PLANE + eo1);
                fK2 = *(const u16x4*)(baseK + (size_t)(cc + 3) * PLANE + eo2);
                fQ1 = *(const u16x4*)(baseQ + (size_t)(cc + 3) * PLANE + eo1);
                fQ2 = *(const u16x4*)(baseQ + (size_t)(cc + 3) * PLANE + eo2);
            } else if (cc == 13) {   // tail: prefetch V planes 0 and 1
                fK1 = *(const u16x4*)(baseV + eo1);
                fK2 = *(const u16x4*)(baseV + eo2);
                fQ1 = *(const u16x4*)(baseV + (size_t)PLANE + eo1);
                fQ2 = *(const u16x4*)(baseV + (size_t)PLANE + eo2);
            }
        }
        const int ch = h * 16 + cc;
        const float* qb = &QB[h][buf][j];
        const float* kb = &KB[h][buf][j];
        float qa0 = 0.f, qa1 = 0.f, qa2 = 0.f, qa3 = 0.f, qa4 = 0.f;
        #pragma unroll
        for (int kw = 0; kw < 5; ++kw) {
            qa0 += rq[0 * 5 + kw] * qb[0 * PW + kw];
            qa1 += rq[1 * 5 + kw] * qb[1 * PW + kw];
            qa2 += rq[2 * 5 + kw] * qb[2 * PW + kw];
            qa3 += rq[3 * 5 + kw] * qb[3 * PW + kw];
            qa4 += rq[4 * 5 + kw] * qb[4 * PW + kw];
        }
        const float qa = (qa0 + qa1) + (qa2 + qa3) + qa4;
        const float qk  = s_gw[32 + ch] * ((qa - cQ) * 0.04f) + s_gb[32 + ch];
        const float qk2 = qk * s_gw[ch];
        sumQ2 += qk2; sumQB += qk * s_gb[ch];
        #pragma unroll
        for (int kh = 0; kh < 5; ++kh)
            #pragma unroll
            for (int kw = 0; kw < 5; ++kw)
                sal[kh * 5 + kw] += qk2 * kb[kh * PW + kw];
        LDS_FENCE();
    }
    // after loop: nK = V plane 0, nQ = V plane 1 (rotated in via tail fetch)

    u16x4 vA1 = nQ1, vA2 = nQ2, vB1{0,0,0,0}, vB2{0,0,0,0};
    if (stg) {
        st4(&KB[h][0][eo1], nK1); st4(&KB[h][0][eo2], nK2);   // V0 -> buf0
        vB1 = *(const u16x4*)(baseV + 2 * (size_t)PLANE + eo1);
        vB2 = *(const u16x4*)(baseV + 2 * (size_t)PLANE + eo2);
    }

    // combine channel halves (lanes t <-> t^32)
    sumQ2 += __shfl_xor(sumQ2, 32);
    sumQB += __shfl_xor(sumQB, 32);
    #pragma unroll
    for (int p = 0; p < 25; ++p) sal[p] += __shfl_xor(sal[p], 32);

    #pragma unroll
    for (int p = 0; p < 25; ++p) sal[p] = s_rk[p] * sal[p] - s_ck[p] * sumQ2 + sumQB;

    const float scale = 0.17677669529663687f;  // 1/sqrt(32)
    float mmax = -3.4e38f;
    #pragma unroll
    for (int p = 0; p < 25; ++p) { sal[p] *= scale; mmax = fmaxf(mmax, sal[p]); }
    float ssum = 0.f;
    #pragma unroll
    for (int p = 0; p < 25; ++p) { sal[p] = __expf(sal[p] - mmax); ssum += sal[p]; }
    const float rs = 1.f / ssum;
    float cV2 = 0.f;
    #pragma unroll
    for (int p = 0; p < 25; ++p) {
        const float m = sal[p] * rs;
        sal[p] = m * s_rv[p];        // reuse sal as V-tap weights
        cV2 += m * s_cv[p];
    }
    LDS_FENCE();   // V0 staged above is visible

    for (int cc = 0; cc < 16; ++cc) {
        const int buf = cc & 1;
        if (stg && cc < 15) {
            st4(&KB[h][buf ^ 1][eo1], vA1); st4(&KB[h][buf ^ 1][eo2], vA2);
            vA1 = vB1; vA2 = vB2;
            if (cc < 13) {
                vB1 = *(const u16x4*)(baseV + (size_t)(cc + 3) * PLANE + eo1);
                vB2 = *(const u16x4*)(baseV + (size_t)(cc + 3) * PLANE + eo2);
            }
        }
        const int v = h * 16 + cc;
        const float* vb = &KB[h][buf][j];
        float a0 = 0.f, a1 = 0.f, a2 = 0.f, a3 = 0.f, a4 = 0.f;
        #pragma unroll
        for (int kw = 0; kw < 5; ++kw) {
            a0 += sal[0 * 5 + kw] * vb[0 * PW + kw];
            a1 += sal[1 * 5 + kw] * vb[1 * PW + kw];
            a2 += sal[2 * 5 + kw] * vb[2 * PW + kw];
            a3 += sal[3 * 5 + kw] * vb[3 * PW + kw];
            a4 += sal[4 * 5 + kw] * vb[4 * PW + kw];
        }
        const float acc = (a0 + a1) + (a2 + a3) + a4;
        out[((size_t)(b * 256 + n * 32 + v) * 32 + i0) * 32 + j] =
            s_gw[64 + v] * acc + (s_gb[64 + v] - s_gw[64 + v] * cV2);
        LDS_FENCE();
    }
}

extern "C" void kernel_launch(void* const* d_in, const int* in_sizes, int n_in,
                              void* d_out, int out_size, void* d_ws, size_t ws_size,
                              hipStream_t stream) {
    const float* x      = (const float*)d_in[0];
    const float* conv_w = (const float*)d_in[1];
    const float* conv_b = (const float*)d_in[2];
    const float* gn_w   = (const float*)d_in[3];
    const float* gn_b   = (const float*)d_in[4];
    float* out = (float*)d_out;

    // ws: attn bf16 padded | rowAgg f32
    ushort_t* attn    = (ushort_t*)d_ws;                    // 8,847,360 ushorts
    float*    rowAgg  = (float*)(attn + 8847360);           // 61,440

    conv_gemm<<<dim3(128, 12), 256, 0, stream>>>(conv_w, x, conv_b, attn, rowAgg);
    local_attn<<<2048, 64, 0, stream>>>(attn, rowAgg, gn_w, gn_b, out);
}

// Round 12
// 123.836 us; speedup vs baseline: 1.0605x; 1.0605x over previous
//
#include <hip/hip_runtime.h>
#include <hip/hip_bf16.h>

#define B_    8
#define CIN   256
#define COUT  768
#define G_    24
#define PW    40         // padded row width (16B-aligned rows)
#define PLANE 1440       // 40*36
#define EPS_  1e-5f

typedef float f32x4 __attribute__((ext_vector_type(4)));
typedef short s16x8 __attribute__((ext_vector_type(8)));
typedef unsigned short ushort_t;
typedef unsigned short u16x4 __attribute__((ext_vector_type(4)));
typedef unsigned long long ull_t;

// LDS-only fence: compiler reordering barrier + s_waitcnt lgkmcnt(0).
// Does NOT wait vmcnt -> global prefetch loads stay in flight.
#define LDS_FENCE() do { asm volatile("" ::: "memory"); \
                         __builtin_amdgcn_s_waitcnt(0xC07F); \
                         asm volatile("" ::: "memory"); } while (0)

static __device__ __forceinline__ ushort_t f2bf(float f) {
    union { float f; unsigned u; } a; a.f = f;
    const unsigned u = a.u;
    const unsigned r = u + 0x7FFFu + ((u >> 16) & 1u);
    return (ushort_t)(r >> 16);
}
static __device__ __forceinline__ float bf2f(ushort_t h) {
    union { unsigned u; float f; } a; a.u = ((unsigned)h) << 16; return a.f;
}
static __device__ __forceinline__ void st4(float* dst, u16x4 v) {
    *(f32x4*)dst = f32x4{ bf2f(v[0]), bf2f(v[1]), bf2f(v[2]), bf2f(v[3]) };
}
static __device__ __forceinline__ unsigned pk2(float lo, float hi) {
    return (unsigned)f2bf(lo) | ((unsigned)f2bf(hi) << 16);
}

// ---------------- Kernel 1: fused prep + bf16 MFMA GEMM -> attn + rowAgg -----
__launch_bounds__(256)
__global__ void conv_gemm(const float* __restrict__ wsrc, const float* __restrict__ x,
                          const float* __restrict__ bias, ushort_t* __restrict__ attn,
                          float* __restrict__ rowAgg) {
    const int t = threadIdx.x;
    const int wv = t >> 6, lane = t & 63;
    const int q = lane >> 4, l15 = lane & 15;
    const int m0 = blockIdx.y * 64;
    const int mw = wv * 16;
    const int n_t = blockIdx.x * 64;
    const int b = n_t >> 10, nl0 = n_t & 1023;
    const int y0 = nl0 >> 5;

    __shared__ ushort_t Bs[64][264];     // [n][k] bf16, row stride 264 hw (33792 B)
    ushort_t (*Ct)[2][44] = (ushort_t (*)[2][44])(&Bs[0][0]);
    float (*red)[11]      = (float (*)[11])((char*)(&Bs[0][0]) + 64 * 2 * 44 * 2);

    // ---- stage B: x[b][k][nl0..nl0+63] fp32 -> Bs[n][k] bf16 (transpose+cvt)
    {
        const int half = t >> 7;
        const int kp = t & 127;
        const int k2 = kp * 2;
        const float* xr0 = x + (size_t)b * (CIN * 1024) + (size_t)k2 * 1024 + nl0 + half * 32;
        const float* xr1 = xr0 + 1024;
        #pragma unroll
        for (int c = 0; c < 8; ++c) {
            const float4 u0 = *(const float4*)(xr0 + c * 4);
            const float4 u1 = *(const float4*)(xr1 + c * 4);
            const int nn = half * 32 + c * 4;
            *(unsigned*)&Bs[nn + 0][k2] = pk2(u0.x, u1.x);
            *(unsigned*)&Bs[nn + 1][k2] = pk2(u0.y, u1.y);
            *(unsigned*)&Bs[nn + 2][k2] = pk2(u0.z, u1.z);
            *(unsigned*)&Bs[nn + 3][k2] = pk2(u0.w, u1.w);
        }
    }
    __syncthreads();

    const float* aPf = wsrc + (size_t)(m0 + mw + l15) * 256 + q * 8;

    f32x4 acc[4] = {{0,0,0,0},{0,0,0,0},{0,0,0,0},{0,0,0,0}};
    #pragma unroll
    for (int k0 = 0; k0 < 256; k0 += 32) {
        const float4 af0 = *(const float4*)(aPf + k0);
        const float4 af1 = *(const float4*)(aPf + k0 + 4);
        s16x8 a;
        a[0] = (short)f2bf(af0.x); a[1] = (short)f2bf(af0.y);
        a[2] = (short)f2bf(af0.z); a[3] = (short)f2bf(af0.w);
        a[4] = (short)f2bf(af1.x); a[5] = (short)f2bf(af1.y);
        a[6] = (short)f2bf(af1.z); a[7] = (short)f2bf(af1.w);
        const int kk = k0 + q * 8;
        const s16x8 b0 = *(const s16x8*)&Bs[l15 +  0][kk];
        const s16x8 b1 = *(const s16x8*)&Bs[l15 + 16][kk];
        const s16x8 b2 = *(const s16x8*)&Bs[l15 + 32][kk];
        const s16x8 b3 = *(const s16x8*)&Bs[l15 + 48][kk];
        acc[0] = __builtin_amdgcn_mfma_f32_16x16x32_bf16(a, b0, acc[0], 0, 0, 0);
        acc[1] = __builtin_amdgcn_mfma_f32_16x16x32_bf16(a, b1, acc[1], 0, 0, 0);
        acc[2] = __builtin_amdgcn_mfma_f32_16x16x32_bf16(a, b2, acc[2], 0, 0, 0);
        acc[3] = __builtin_amdgcn_mfma_f32_16x16x32_bf16(a, b3, acc[3], 0, 0, 0);
    }
    __syncthreads();   // Bs dead; Ct/red aliasing begins

    float bb[4];
    #pragma unroll
    for (int r = 0; r < 4; ++r) bb[r] = bias[m0 + mw + q * 4 + r];
    #pragma unroll
    for (int j = 0; j < 4; ++j) {
        const int yy = j >> 1, xx = (j & 1) * 16 + l15;
        #pragma unroll
        for (int r = 0; r < 4; ++r)
            Ct[mw + q * 4 + r][yy][2 + xx] = f2bf(acc[j][r] + bb[r]);
    }
    #pragma unroll
    for (int it = 0; it < 2; ++it) {
        const int id = it * 256 + t;
        const int m = id >> 3, yy = (id >> 2) & 1, pos = id & 3;
        const int us = (pos == 0) ? 0 : (32 + 2 * pos);
        *(unsigned*)&Ct[m][yy][us] = 0u;
    }
    __syncthreads();

    ushort_t* pb = attn + ((size_t)(b * COUT + m0)) * PLANE;
    #pragma unroll
    for (int it = 0; it < 5; ++it) {
        const int id = it * 256 + t;
        const int m = id / 20, rem = id % 20, yy = rem / 10, s = rem % 10;
        const ull_t v = *(const ull_t*)&Ct[m][yy][s * 4];
        *(ull_t*)(pb + (size_t)m * PLANE + (y0 + yy + 2) * PW + s * 4) = v;
    }
    if (y0 == 0 || y0 == 30) {
        const int rowA = (y0 == 0) ? 0 : 34;
        #pragma unroll
        for (int it = 0; it < 5; ++it) {
            const int id = it * 256 + t;
            const int m = id / 20, rem = id % 20, yy = rem / 10, s = rem % 10;
            *(ull_t*)(pb + (size_t)m * PLANE + (rowA + yy) * PW + s * 4) = 0ull;
        }
    }

    if (t < 128) {
        const int gi = t >> 6, yy = (t >> 5) & 1, c = t & 31;
        const int m = gi * 32 + c;
        float lin = 0.f, sq = 0.f, e0 = 0.f, e1 = 0.f, e30 = 0.f, e31 = 0.f;
        #pragma unroll
        for (int u = 0; u < 9; ++u) {
            const ull_t vv = *(const ull_t*)&Ct[m][yy][u * 4];
            const unsigned lo = (unsigned)vv, hi = (unsigned)(vv >> 32);
            union { unsigned u; float f; } f0, f1, f2, f3;
            f0.u = lo << 16; f1.u = lo & 0xffff0000u;
            f2.u = hi << 16; f3.u = hi & 0xffff0000u;
            lin += (f0.f + f1.f) + (f2.f + f3.f);
            sq  += (f0.f * f0.f + f1.f * f1.f) + (f2.f * f2.f + f3.f * f3.f);
            if (u == 0) { e0 = f2.f; e1 = f3.f; }
            if (u == 8) { e30 = f0.f; e31 = f1.f; }
        }
        red[t][0] = lin; red[t][1] = sq;
        red[t][2] = e0;  red[t][3] = e0 * e0;
        red[t][4] = e1;  red[t][5] = e1 * e1;
        red[t][6] = e30; red[t][7] = e30 * e30;
        red[t][8] = e31; red[t][9] = e31 * e31;
    }
    __syncthreads();
    if (t < 40) {
        const int s = t % 10, gy = t / 10;
        const int gi = gy >> 1, yy = gy & 1;
        float sum = 0.f;
        #pragma unroll
        for (int c = 0; c < 32; ++c) sum += red[gi * 64 + yy * 32 + c][s];
        const int g = blockIdx.y * 2 + gi;
        rowAgg[(((size_t)b * G_ + g) * 32 + (y0 + yy)) * 10 + s] = sum;
    }
}

// ---------------- Kernel 2: local attention — 1-wave blocks, fused GN-stats
// finalize (from rowAgg), intra-wave channel split, double-buffered LDS,
// fence-only pipeline. NATURAL block order (no XCD swizzle — R11 showed the
// swizzle cost ~9 us; dispatch mapping assumption was wrong). ---------------
__launch_bounds__(64)
__global__ void local_attn(const ushort_t* __restrict__ attn,
                           const float* __restrict__ rowAgg,
                           const float* __restrict__ gn_w, const float* __restrict__ gn_b,
                           float* __restrict__ out) {
    const int wid = blockIdx.x;          // 2048, natural order
    const int b = wid >> 8;
    const int n = (wid >> 5) & 7;
    const int i0 = wid & 31;             // image row
    const int t = threadIdx.x;           // 64
    const int h = t >> 5;                // channel half
    const int j = t & 31;                // pixel column

    __shared__ float KB[2][2][208];      // [half][buf][5 rows x 40 + pad]
    __shared__ float QB[2][2][208];
    __shared__ float rpL[96][5], rp2L[96][5];   // per (gi*32+y) window col-sums
    __shared__ float s_m[75], s_r[75];          // per (gi*25+p) mean / rstd
    __shared__ float s_rq[25], s_mq[25], s_rk[25], s_ck[25], s_rv[25], s_cv[25];
    __shared__ float s_gw[96], s_gb[96];

    s_gw[t] = gn_w[n * 96 + t];
    s_gb[t] = gn_b[n * 96 + t];
    if (t < 32) {
        s_gw[64 + t] = gn_w[n * 96 + 64 + t];
        s_gb[64 + t] = gn_b[n * 96 + 64 + t];
    }

    // ---- fused gnfin, phase 1: per-(group,row) window column sums ----------
    const float* rab = rowAgg + (size_t)((b * G_ + n * 3) * 32) * 10;
    #pragma unroll
    for (int pass = 0; pass < 2; ++pass) {
        const int e = (pass == 0) ? t : 64 + t;   // e = gi*32 + y, 96 tasks
        if (pass == 0 || t < 32) {
            const float* a = rab + (size_t)e * 10;
            const float S = a[0], Sq = a[1];
            const float e0 = a[2], q0 = a[3], e1 = a[4], q1 = a[5];
            const float e30 = a[6], q30 = a[7], e31 = a[8], q31 = a[9];
            rpL[e][0] = S - e30 - e31; rpL[e][1] = S - e31; rpL[e][2] = S;
            rpL[e][3] = S - e0;        rpL[e][4] = S - e0 - e1;
            rp2L[e][0] = Sq - q30 - q31; rp2L[e][1] = Sq - q31; rp2L[e][2] = Sq;
            rp2L[e][3] = Sq - q0;        rp2L[e][4] = Sq - q0 - q1;
        }
    }
    __syncthreads();

    // ---- fused gnfin, phase 2: 75 (group,window) mean/rstd entries ---------
    #pragma unroll
    for (int pass = 0; pass < 2; ++pass) {
        const int e = (pass == 0) ? t : 64 + t;
        if (e < 75) {
            const int gi = e / 25, p = e % 25;
            const int kw = p % 5, kh = p / 5;
            const int rb = gi * 32;
            float cs = 0.f, cs2 = 0.f;
            #pragma unroll
            for (int yy = 0; yy < 32; ++yy) { cs += rpL[rb + yy][kw]; cs2 += rp2L[rb + yy][kw]; }
            if (kh == 0)      { cs -= rpL[rb + 30][kw] + rpL[rb + 31][kw]; cs2 -= rp2L[rb + 30][kw] + rp2L[rb + 31][kw]; }
            else if (kh == 1) { cs -= rpL[rb + 31][kw];                    cs2 -= rp2L[rb + 31][kw]; }
            else if (kh == 3) { cs -= rpL[rb + 0][kw];                     cs2 -= rp2L[rb + 0][kw]; }
            else if (kh == 4) { cs -= rpL[rb + 0][kw] + rpL[rb + 1][kw];   cs2 -= rp2L[rb + 0][kw] + rp2L[rb + 1][kw]; }
            const float inv_n = 1.f / 32768.f;
            const float mean = cs * inv_n;
            const float var  = cs2 * inv_n - mean * mean;
            s_m[e] = mean;
            s_r[e] = rsqrtf(var + EPS_);
        }
    }
    __syncthreads();

    if (t < 25) {
        const float mK = s_m[t],      rK = s_r[t];
        const float mQ = s_m[25 + t], rQ = s_r[25 + t];
        const float mV = s_m[50 + t], rV = s_r[50 + t];
        s_rk[t] = rK; s_ck[t] = mK * rK;
        s_rq[t] = rQ; s_mq[t] = mQ * rQ;
        s_rv[t] = rV; s_cv[t] = mV * rV;
    }
    __syncthreads();

    float rq[25]; float cQ = 0.f;
    #pragma unroll
    for (int p = 0; p < 25; ++p) { rq[p] = s_rq[p]; cQ += s_mq[p]; }

    const ushort_t* regB = attn + (size_t)(b * COUT + n * 96) * PLANE + i0 * PW;
    const bool stg = (j < 25);
    const int eo1 = j * 4, eo2 = (j + 25) * 4;

    const ushort_t* baseK = regB + (size_t)(h * 16) * PLANE;
    const ushort_t* baseQ = regB + (size_t)(32 + h * 16) * PLANE;
    const ushort_t* baseV = regB + (size_t)(64 + h * 16) * PLANE;

    u16x4 nK1{0,0,0,0}, nK2{0,0,0,0}, nQ1{0,0,0,0}, nQ2{0,0,0,0};
    u16x4 fK1{0,0,0,0}, fK2{0,0,0,0}, fQ1{0,0,0,0}, fQ2{0,0,0,0};
    if (stg) {
        const u16x4 a1 = *(const u16x4*)(baseK + eo1), a2 = *(const u16x4*)(baseK + eo2);
        const u16x4 q1 = *(const u16x4*)(baseQ + eo1), q2 = *(const u16x4*)(baseQ + eo2);
        st4(&KB[h][0][eo1], a1); st4(&KB[h][0][eo2], a2);
        st4(&QB[h][0][eo1], q1); st4(&QB[h][0][eo2], q2);
        nK1 = *(const u16x4*)(baseK + PLANE + eo1); nK2 = *(const u16x4*)(baseK + PLANE + eo2);
        nQ1 = *(const u16x4*)(baseQ + PLANE + eo1); nQ2 = *(const u16x4*)(baseQ + PLANE + eo2);
        fK1 = *(const u16x4*)(baseK + 2 * (size_t)PLANE + eo1);
        fK2 = *(const u16x4*)(baseK + 2 * (size_t)PLANE + eo2);
        fQ1 = *(const u16x4*)(baseQ + 2 * (size_t)PLANE + eo1);
        fQ2 = *(const u16x4*)(baseQ + 2 * (size_t)PLANE + eo2);
    }
    LDS_FENCE();

    float sal[25];
    #pragma unroll
    for (int p = 0; p < 25; ++p) sal[p] = 0.f;
    float sumQ2 = 0.f, sumQB = 0.f;

    for (int cc = 0; cc < 16; ++cc) {
        const int buf = cc & 1;
        if (stg && cc < 15) {
            st4(&KB[h][buf ^ 1][eo1], nK1); st4(&KB[h][buf ^ 1][eo2], nK2);
            st4(&QB[h][buf ^ 1][eo1], nQ1); st4(&QB[h][buf ^ 1][eo2], nQ2);
            nK1 = fK1; nK2 = fK2; nQ1 = fQ1; nQ2 = fQ2;
            if (cc < 13) {
                fK1 = *(const u16x4*)(baseK + (size_t)(cc + 3) * PLANE + eo1);
                fK2 = *(const u16x4*)(baseK + (size_t)(cc + 3) * PLANE + eo2);
                fQ1 = *(const u16x4*)(baseQ + (size_t)(cc + 3) * PLANE + eo1);
                fQ2 = *(const u16x4*)(baseQ + (size_t)(cc + 3) * PLANE + eo2);
            } else if (cc == 13) {   // tail: prefetch V planes 0 and 1
                fK1 = *(const u16x4*)(baseV + eo1);
                fK2 = *(const u16x4*)(baseV + eo2);
                fQ1 = *(const u16x4*)(baseV + (size_t)PLANE + eo1);
                fQ2 = *(const u16x4*)(baseV + (size_t)PLANE + eo2);
            }
        }
        const int ch = h * 16 + cc;
        const float* qb = &QB[h][buf][j];
        const float* kb = &KB[h][buf][j];
        float qa0 = 0.f, qa1 = 0.f, qa2 = 0.f, qa3 = 0.f, qa4 = 0.f;
        #pragma unroll
        for (int kw = 0; kw < 5; ++kw) {
            qa0 += rq[0 * 5 + kw] * qb[0 * PW + kw];
            qa1 += rq[1 * 5 + kw] * qb[1 * PW + kw];
            qa2 += rq[2 * 5 + kw] * qb[2 * PW + kw];
            qa3 += rq[3 * 5 + kw] * qb[3 * PW + kw];
            qa4 += rq[4 * 5 + kw] * qb[4 * PW + kw];
        }
        const float qa = (qa0 + qa1) + (qa2 + qa3) + qa4;
        const float qk  = s_gw[32 + ch] * ((qa - cQ) * 0.04f) + s_gb[32 + ch];
        const float qk2 = qk * s_gw[ch];
        sumQ2 += qk2; sumQB += qk * s_gb[ch];
        #pragma unroll
        for (int kh = 0; kh < 5; ++kh)
            #pragma unroll
            for (int kw = 0; kw < 5; ++kw)
                sal[kh * 5 + kw] += qk2 * kb[kh * PW + kw];
        LDS_FENCE();
    }
    // after loop: nK = V plane 0, nQ = V plane 1 (rotated in via tail fetch)

    u16x4 vA1 = nQ1, vA2 = nQ2, vB1{0,0,0,0}, vB2{0,0,0,0};
    if (stg) {
        st4(&KB[h][0][eo1], nK1); st4(&KB[h][0][eo2], nK2);   // V0 -> buf0
        vB1 = *(const u16x4*)(baseV + 2 * (size_t)PLANE + eo1);
        vB2 = *(const u16x4*)(baseV + 2 * (size_t)PLANE + eo2);
    }

    // combine channel halves (lanes t <-> t^32)
    sumQ2 += __shfl_xor(sumQ2, 32);
    sumQB += __shfl_xor(sumQB, 32);
    #pragma unroll
    for (int p = 0; p < 25; ++p) sal[p] += __shfl_xor(sal[p], 32);

    #pragma unroll
    for (int p = 0; p < 25; ++p) sal[p] = s_rk[p] * sal[p] - s_ck[p] * sumQ2 + sumQB;

    const float scale = 0.17677669529663687f;  // 1/sqrt(32)
    float mmax = -3.4e38f;
    #pragma unroll
    for (int p = 0; p < 25; ++p) { sal[p] *= scale; mmax = fmaxf(mmax, sal[p]); }
    float ssum = 0.f;
    #pragma unroll
    for (int p = 0; p < 25; ++p) { sal[p] = __expf(sal[p] - mmax); ssum += sal[p]; }
    const float rs = 1.f / ssum;
    float cV2 = 0.f;
    #pragma unroll
    for (int p = 0; p < 25; ++p) {
        const float m = sal[p] * rs;
        sal[p] = m * s_rv[p];        // reuse sal as V-tap weights
        cV2 += m * s_cv[p];
    }
    LDS_FENCE();   // V0 staged above is visible

    for (int cc = 0; cc < 16; ++cc) {
        const int buf = cc & 1;
        if (stg && cc < 15) {
            st4(&KB[h][buf ^ 1][eo1], vA1); st4(&KB[h][buf ^ 1][eo2], vA2);
            vA1 = vB1; vA2 = vB2;
            if (cc < 13) {
                vB1 = *(const u16x4*)(baseV + (size_t)(cc + 3) * PLANE + eo1);
                vB2 = *(const u16x4*)(baseV + (size_t)(cc + 3) * PLANE + eo2);
            }
        }
        const int v = h * 16 + cc;
        const float* vb = &KB[h][buf][j];
        float a0 = 0.f, a1 = 0.f, a2 = 0.f, a3 = 0.f, a4 = 0.f;
        #pragma unroll
        for (int kw = 0; kw < 5; ++kw) {
            a0 += sal[0 * 5 + kw] * vb[0 * PW + kw];
            a1 += sal[1 * 5 + kw] * vb[1 * PW + kw];
            a2 += sal[2 * 5 + kw] * vb[2 * PW + kw];
            a3 += sal[3 * 5 + kw] * vb[3 * PW + kw];
            a4 += sal[4 * 5 + kw] * vb[4 * PW + kw];
        }
        const float acc = (a0 + a1) + (a2 + a3) + a4;
        out[((size_t)(b * 256 + n * 32 + v) * 32 + i0) * 32 + j] =
            s_gw[64 + v] * acc + (s_gb[64 + v] - s_gw[64 + v] * cV2);
        LDS_FENCE();
    }
}

extern "C" void kernel_launch(void* const* d_in, const int* in_sizes, int n_in,
                              void* d_out, int out_size, void* d_ws, size_t ws_size,
                              hipStream_t stream) {
    const float* x      = (const float*)d_in[0];
    const float* conv_w = (const float*)d_in[1];
    const float* conv_b = (const float*)d_in[2];
    const float* gn_w   = (const float*)d_in[3];
    const float* gn_b   = (const float*)d_in[4];
    float* out = (float*)d_out;

    // ws: attn bf16 padded | rowAgg f32
    ushort_t* attn    = (ushort_t*)d_ws;                    // 8,847,360 ushorts
    float*    rowAgg  = (float*)(attn + 8847360);           // 61,440

    conv_gemm<<<dim3(128, 12), 256, 0, stream>>>(conv_w, x, conv_b, attn, rowAgg);
    local_attn<<<2048, 64, 0, stream>>>(attn, rowAgg, gn_w, gn_b, out);
}

// Round 13
// 119.185 us; speedup vs baseline: 1.1019x; 1.0390x over previous
//
#include <hip/hip_runtime.h>
#include <hip/hip_bf16.h>

#define B_    8
#define CIN   256
#define COUT  768
#define G_    24
#define PW    40         // padded row width (16B-aligned rows)
#define PLANE 1440       // 40*36
#define EPS_  1e-5f

typedef float f32x4 __attribute__((ext_vector_type(4)));
typedef short s16x8 __attribute__((ext_vector_type(8)));
typedef unsigned short ushort_t;
typedef unsigned short u16x4 __attribute__((ext_vector_type(4)));
typedef unsigned long long ull_t;

// LDS-only fence: compiler reordering barrier + s_waitcnt lgkmcnt(0).
// Does NOT wait vmcnt -> global prefetch loads stay in flight.
#define LDS_FENCE() do { asm volatile("" ::: "memory"); \
                         __builtin_amdgcn_s_waitcnt(0xC07F); \
                         asm volatile("" ::: "memory"); } while (0)

static __device__ __forceinline__ ushort_t f2bf(float f) {
    union { float f; unsigned u; } a; a.f = f;
    const unsigned u = a.u;
    const unsigned r = u + 0x7FFFu + ((u >> 16) & 1u);
    return (ushort_t)(r >> 16);
}
static __device__ __forceinline__ float bf2f(ushort_t h) {
    union { unsigned u; float f; } a; a.u = ((unsigned)h) << 16; return a.f;
}
static __device__ __forceinline__ void st4(float* dst, u16x4 v) {
    *(f32x4*)dst = f32x4{ bf2f(v[0]), bf2f(v[1]), bf2f(v[2]), bf2f(v[3]) };
}
static __device__ __forceinline__ unsigned pk2(float lo, float hi) {
    return (unsigned)f2bf(lo) | ((unsigned)f2bf(hi) << 16);
}

// ---------------- Kernel 1: fused prep + bf16 MFMA GEMM -> attn + rowAgg -----
__launch_bounds__(256)
__global__ void conv_gemm(const float* __restrict__ wsrc, const float* __restrict__ x,
                          const float* __restrict__ bias, ushort_t* __restrict__ attn,
                          float* __restrict__ rowAgg) {
    const int t = threadIdx.x;
    const int wv = t >> 6, lane = t & 63;
    const int q = lane >> 4, l15 = lane & 15;
    const int m0 = blockIdx.y * 64;
    const int mw = wv * 16;
    const int n_t = blockIdx.x * 64;
    const int b = n_t >> 10, nl0 = n_t & 1023;
    const int y0 = nl0 >> 5;

    __shared__ ushort_t Bs[64][264];     // [n][k] bf16, row stride 264 hw (33792 B)
    ushort_t (*Ct)[2][44] = (ushort_t (*)[2][44])(&Bs[0][0]);
    float (*red)[11]      = (float (*)[11])((char*)(&Bs[0][0]) + 64 * 2 * 44 * 2);

    // ---- stage B: x[b][k][nl0..nl0+63] fp32 -> Bs[n][k] bf16 (transpose+cvt)
    {
        const int half = t >> 7;
        const int kp = t & 127;
        const int k2 = kp * 2;
        const float* xr0 = x + (size_t)b * (CIN * 1024) + (size_t)k2 * 1024 + nl0 + half * 32;
        const float* xr1 = xr0 + 1024;
        #pragma unroll
        for (int c = 0; c < 8; ++c) {
            const float4 u0 = *(const float4*)(xr0 + c * 4);
            const float4 u1 = *(const float4*)(xr1 + c * 4);
            const int nn = half * 32 + c * 4;
            *(unsigned*)&Bs[nn + 0][k2] = pk2(u0.x, u1.x);
            *(unsigned*)&Bs[nn + 1][k2] = pk2(u0.y, u1.y);
            *(unsigned*)&Bs[nn + 2][k2] = pk2(u0.z, u1.z);
            *(unsigned*)&Bs[nn + 3][k2] = pk2(u0.w, u1.w);
        }
    }
    __syncthreads();

    const float* aPf = wsrc + (size_t)(m0 + mw + l15) * 256 + q * 8;

    f32x4 acc[4] = {{0,0,0,0},{0,0,0,0},{0,0,0,0},{0,0,0,0}};
    #pragma unroll
    for (int k0 = 0; k0 < 256; k0 += 32) {
        const float4 af0 = *(const float4*)(aPf + k0);
        const float4 af1 = *(const float4*)(aPf + k0 + 4);
        s16x8 a;
        a[0] = (short)f2bf(af0.x); a[1] = (short)f2bf(af0.y);
        a[2] = (short)f2bf(af0.z); a[3] = (short)f2bf(af0.w);
        a[4] = (short)f2bf(af1.x); a[5] = (short)f2bf(af1.y);
        a[6] = (short)f2bf(af1.z); a[7] = (short)f2bf(af1.w);
        const int kk = k0 + q * 8;
        const s16x8 b0 = *(const s16x8*)&Bs[l15 +  0][kk];
        const s16x8 b1 = *(const s16x8*)&Bs[l15 + 16][kk];
        const s16x8 b2 = *(const s16x8*)&Bs[l15 + 32][kk];
        const s16x8 b3 = *(const s16x8*)&Bs[l15 + 48][kk];
        acc[0] = __builtin_amdgcn_mfma_f32_16x16x32_bf16(a, b0, acc[0], 0, 0, 0);
        acc[1] = __builtin_amdgcn_mfma_f32_16x16x32_bf16(a, b1, acc[1], 0, 0, 0);
        acc[2] = __builtin_amdgcn_mfma_f32_16x16x32_bf16(a, b2, acc[2], 0, 0, 0);
        acc[3] = __builtin_amdgcn_mfma_f32_16x16x32_bf16(a, b3, acc[3], 0, 0, 0);
    }
    __syncthreads();   // Bs dead; Ct/red aliasing begins

    float bb[4];
    #pragma unroll
    for (int r = 0; r < 4; ++r) bb[r] = bias[m0 + mw + q * 4 + r];
    #pragma unroll
    for (int j = 0; j < 4; ++j) {
        const int yy = j >> 1, xx = (j & 1) * 16 + l15;
        #pragma unroll
        for (int r = 0; r < 4; ++r)
            Ct[mw + q * 4 + r][yy][2 + xx] = f2bf(acc[j][r] + bb[r]);
    }
    #pragma unroll
    for (int it = 0; it < 2; ++it) {
        const int id = it * 256 + t;
        const int m = id >> 3, yy = (id >> 2) & 1, pos = id & 3;
        const int us = (pos == 0) ? 0 : (32 + 2 * pos);
        *(unsigned*)&Ct[m][yy][us] = 0u;
    }
    __syncthreads();

    ushort_t* pb = attn + ((size_t)(b * COUT + m0)) * PLANE;
    #pragma unroll
    for (int it = 0; it < 5; ++it) {
        const int id = it * 256 + t;
        const int m = id / 20, rem = id % 20, yy = rem / 10, s = rem % 10;
        const ull_t v = *(const ull_t*)&Ct[m][yy][s * 4];
        *(ull_t*)(pb + (size_t)m * PLANE + (y0 + yy + 2) * PW + s * 4) = v;
    }
    if (y0 == 0 || y0 == 30) {
        const int rowA = (y0 == 0) ? 0 : 34;
        #pragma unroll
        for (int it = 0; it < 5; ++it) {
            const int id = it * 256 + t;
            const int m = id / 20, rem = id % 20, yy = rem / 10, s = rem % 10;
            *(ull_t*)(pb + (size_t)m * PLANE + (rowA + yy) * PW + s * 4) = 0ull;
        }
    }

    if (t < 128) {
        const int gi = t >> 6, yy = (t >> 5) & 1, c = t & 31;
        const int m = gi * 32 + c;
        float lin = 0.f, sq = 0.f, e0 = 0.f, e1 = 0.f, e30 = 0.f, e31 = 0.f;
        #pragma unroll
        for (int u = 0; u < 9; ++u) {
            const ull_t vv = *(const ull_t*)&Ct[m][yy][u * 4];
            const unsigned lo = (unsigned)vv, hi = (unsigned)(vv >> 32);
            union { unsigned u; float f; } f0, f1, f2, f3;
            f0.u = lo << 16; f1.u = lo & 0xffff0000u;
            f2.u = hi << 16; f3.u = hi & 0xffff0000u;
            lin += (f0.f + f1.f) + (f2.f + f3.f);
            sq  += (f0.f * f0.f + f1.f * f1.f) + (f2.f * f2.f + f3.f * f3.f);
            if (u == 0) { e0 = f2.f; e1 = f3.f; }
            if (u == 8) { e30 = f0.f; e31 = f1.f; }
        }
        red[t][0] = lin; red[t][1] = sq;
        red[t][2] = e0;  red[t][3] = e0 * e0;
        red[t][4] = e1;  red[t][5] = e1 * e1;
        red[t][6] = e30; red[t][7] = e30 * e30;
        red[t][8] = e31; red[t][9] = e31 * e31;
    }
    __syncthreads();
    if (t < 40) {
        const int s = t % 10, gy = t / 10;
        const int gi = gy >> 1, yy = gy & 1;
        float sum = 0.f;
        #pragma unroll
        for (int c = 0; c < 32; ++c) sum += red[gi * 64 + yy * 32 + c][s];
        const int g = blockIdx.y * 2 + gi;
        rowAgg[(((size_t)b * G_ + g) * 32 + (y0 + yy)) * 10 + s] = sum;
    }
}

// ---------------- Kernel 2: local attention — 2-wave blocks, 2-row slabs.
// Wave = channel half covering all 64 px; wave-private double-buffered LDS
// staging with fence-only pipeline (no barriers in loops); ONE __syncthreads
// for the cross-wave sal exchange. Fused GN-stats finalize from rowAgg. -------
__launch_bounds__(128)
__global__ void local_attn(const ushort_t* __restrict__ attn,
                           const float* __restrict__ rowAgg,
                           const float* __restrict__ gn_w, const float* __restrict__ gn_b,
                           float* __restrict__ out) {
    const int wid = blockIdx.x;          // 1024 = b(8) x n(8) x slab(16)
    const int b = wid >> 7;
    const int n = (wid >> 4) & 7;
    const int i0 = (wid & 15) * 2;       // first image row of the 2-row slab
    const int t = threadIdx.x;           // 128
    const int h = t >> 6;                // wave index = channel half
    const int lane = t & 63;
    const int r = lane >> 5;             // row within slab
    const int j = lane & 31;             // pixel column

    __shared__ float KB[2][2][240];      // [half][buf][6 rows x 40]
    __shared__ float QB[2][2][240];
    __shared__ float ex[128][27];        // sal exchange, stride-27 conflict-free
    __shared__ float rpL[96][5], rp2L[96][5];
    __shared__ float s_m[75], s_r[75];
    __shared__ float s_rq[25], s_mq[25], s_rk[25], s_ck[25], s_rv[25], s_cv[25];
    __shared__ float s_gw[96], s_gb[96];

    if (t < 96) { s_gw[t] = gn_w[n * 96 + t]; s_gb[t] = gn_b[n * 96 + t]; }

    // ---- fused gnfin, phase 1: per-(group,row) window column sums ----------
    const float* rab = rowAgg + (size_t)((b * G_ + n * 3) * 32) * 10;
    if (t < 96) {
        const float* a = rab + (size_t)t * 10;
        const float S = a[0], Sq = a[1];
        const float e0 = a[2], q0 = a[3], e1 = a[4], q1 = a[5];
        const float e30 = a[6], q30 = a[7], e31 = a[8], q31 = a[9];
        rpL[t][0] = S - e30 - e31; rpL[t][1] = S - e31; rpL[t][2] = S;
        rpL[t][3] = S - e0;        rpL[t][4] = S - e0 - e1;
        rp2L[t][0] = Sq - q30 - q31; rp2L[t][1] = Sq - q31; rp2L[t][2] = Sq;
        rp2L[t][3] = Sq - q0;        rp2L[t][4] = Sq - q0 - q1;
    }
    __syncthreads();

    // ---- fused gnfin, phase 2: 75 (group,window) mean/rstd entries ---------
    if (t < 75) {
        const int gi = t / 25, p = t % 25;
        const int kw = p % 5, kh = p / 5;
        const int rb = gi * 32;
        float cs = 0.f, cs2 = 0.f;
        #pragma unroll
        for (int yy = 0; yy < 32; ++yy) { cs += rpL[rb + yy][kw]; cs2 += rp2L[rb + yy][kw]; }
        if (kh == 0)      { cs -= rpL[rb + 30][kw] + rpL[rb + 31][kw]; cs2 -= rp2L[rb + 30][kw] + rp2L[rb + 31][kw]; }
        else if (kh == 1) { cs -= rpL[rb + 31][kw];                    cs2 -= rp2L[rb + 31][kw]; }
        else if (kh == 3) { cs -= rpL[rb + 0][kw];                     cs2 -= rp2L[rb + 0][kw]; }
        else if (kh == 4) { cs -= rpL[rb + 0][kw] + rpL[rb + 1][kw];   cs2 -= rp2L[rb + 0][kw] + rp2L[rb + 1][kw]; }
        const float inv_n = 1.f / 32768.f;
        const float mean = cs * inv_n;
        const float var  = cs2 * inv_n - mean * mean;
        s_m[t] = mean;
        s_r[t] = rsqrtf(var + EPS_);
    }
    __syncthreads();

    if (t < 25) {
        const float mK = s_m[t],      rK = s_r[t];
        const float mQ = s_m[25 + t], rQ = s_r[25 + t];
        const float mV = s_m[50 + t], rV = s_r[50 + t];
        s_rk[t] = rK; s_ck[t] = mK * rK;
        s_rq[t] = rQ; s_mq[t] = mQ * rQ;
        s_rv[t] = rV; s_cv[t] = mV * rV;
    }
    __syncthreads();

    float rq[25]; float cQ = 0.f;
    #pragma unroll
    for (int p = 0; p < 25; ++p) { rq[p] = s_rq[p]; cQ += s_mq[p]; }

    // wave-private staging: padded rows i0..i0+5 (240 bf16/plane); 60 stagers
    const ushort_t* regB = attn + (size_t)(b * COUT + n * 96) * PLANE + i0 * PW;
    const bool stg = (lane < 60);
    const int eo = lane * 4;
    const int base = r * PW + j;

    const ushort_t* baseK = regB + (size_t)(h * 16) * PLANE;
    const ushort_t* baseQ = regB + (size_t)(32 + h * 16) * PLANE;
    const ushort_t* baseV = regB + (size_t)(64 + h * 16) * PLANE;

    u16x4 nK{0,0,0,0}, nQ{0,0,0,0}, fK{0,0,0,0}, fQ{0,0,0,0};
    if (stg) {
        const u16x4 c0K = *(const u16x4*)(baseK + eo);
        const u16x4 c0Q = *(const u16x4*)(baseQ + eo);
        st4(&KB[h][0][eo], c0K);
        st4(&QB[h][0][eo], c0Q);
        nK = *(const u16x4*)(baseK + (size_t)PLANE + eo);
        nQ = *(const u16x4*)(baseQ + (size_t)PLANE + eo);
        fK = *(const u16x4*)(baseK + 2 * (size_t)PLANE + eo);
        fQ = *(const u16x4*)(baseQ + 2 * (size_t)PLANE + eo);
    }
    LDS_FENCE();

    float sal[25];
    #pragma unroll
    for (int p = 0; p < 25; ++p) sal[p] = 0.f;
    float sumQ2 = 0.f, sumQB = 0.f;

    for (int cc = 0; cc < 16; ++cc) {
        const int buf = cc & 1;
        if (stg && cc < 15) {
            st4(&KB[h][buf ^ 1][eo], nK);
            st4(&QB[h][buf ^ 1][eo], nQ);
            nK = fK; nQ = fQ;
            if (cc < 13) {
                fK = *(const u16x4*)(baseK + (size_t)(cc + 3) * PLANE + eo);
                fQ = *(const u16x4*)(baseQ + (size_t)(cc + 3) * PLANE + eo);
            } else if (cc == 13) {   // tail: prefetch V planes 0 and 1
                fK = *(const u16x4*)(baseV + eo);
                fQ = *(const u16x4*)(baseV + (size_t)PLANE + eo);
            }
        }
        const int ch = h * 16 + cc;
        const float* qb = &QB[h][buf][base];
        const float* kb = &KB[h][buf][base];
        float qa0 = 0.f, qa1 = 0.f, qa2 = 0.f, qa3 = 0.f, qa4 = 0.f;
        #pragma unroll
        for (int kw = 0; kw < 5; ++kw) {
            qa0 += rq[0 * 5 + kw] * qb[0 * PW + kw];
            qa1 += rq[1 * 5 + kw] * qb[1 * PW + kw];
            qa2 += rq[2 * 5 + kw] * qb[2 * PW + kw];
            qa3 += rq[3 * 5 + kw] * qb[3 * PW + kw];
            qa4 += rq[4 * 5 + kw] * qb[4 * PW + kw];
        }
        const float qa = (qa0 + qa1) + (qa2 + qa3) + qa4;
        const float qk  = s_gw[32 + ch] * ((qa - cQ) * 0.04f) + s_gb[32 + ch];
        const float qk2 = qk * s_gw[ch];
        sumQ2 += qk2; sumQB += qk * s_gb[ch];
        #pragma unroll
        for (int kh = 0; kh < 5; ++kh)
            #pragma unroll
            for (int kw = 0; kw < 5; ++kw)
                sal[kh * 5 + kw] += qk2 * kb[kh * PW + kw];
        LDS_FENCE();
    }
    // after loop: nK = V plane 0, nQ = V plane 1 (rotated in via tail fetch)

    // cross-wave exchange (lane t <-> t^64): write partials + stage V0, barrier
    #pragma unroll
    for (int p = 0; p < 25; ++p) ex[t][p] = sal[p];
    ex[t][25] = sumQ2; ex[t][26] = sumQB;
    if (stg) st4(&KB[h][0][eo], nK);     // V0 -> buf0 (wave-private)
    __syncthreads();
    const int par = t ^ 64;
    #pragma unroll
    for (int p = 0; p < 25; ++p) sal[p] += ex[par][p];
    sumQ2 += ex[par][25]; sumQB += ex[par][26];

    u16x4 vA = nQ, vB{0,0,0,0};
    if (stg) vB = *(const u16x4*)(baseV + 2 * (size_t)PLANE + eo);  // V2 (post-barrier)

    #pragma unroll
    for (int p = 0; p < 25; ++p) sal[p] = s_rk[p] * sal[p] - s_ck[p] * sumQ2 + sumQB;

    const float scale = 0.17677669529663687f;  // 1/sqrt(32)
    float mmax = -3.4e38f;
    #pragma unroll
    for (int p = 0; p < 25; ++p) { sal[p] *= scale; mmax = fmaxf(mmax, sal[p]); }
    float ssum = 0.f;
    #pragma unroll
    for (int p = 0; p < 25; ++p) { sal[p] = __expf(sal[p] - mmax); ssum += sal[p]; }
    const float rs = 1.f / ssum;
    float cV2 = 0.f;
    #pragma unroll
    for (int p = 0; p < 25; ++p) {
        const float m = sal[p] * rs;
        sal[p] = m * s_rv[p];        // reuse sal as V-tap weights
        cV2 += m * s_cv[p];
    }
    LDS_FENCE();

    for (int cc = 0; cc < 16; ++cc) {
        const int buf = cc & 1;
        if (stg && cc < 15) {
            st4(&KB[h][buf ^ 1][eo], vA);
            vA = vB;
            if (cc < 13) vB = *(const u16x4*)(baseV + (size_t)(cc + 3) * PLANE + eo);
        }
        const int v = h * 16 + cc;
        const float* vb = &KB[h][buf][base];
        float a0 = 0.f, a1 = 0.f, a2 = 0.f, a3 = 0.f, a4 = 0.f;
        #pragma unroll
        for (int kw = 0; kw < 5; ++kw) {
            a0 += sal[0 * 5 + kw] * vb[0 * PW + kw];
            a1 += sal[1 * 5 + kw] * vb[1 * PW + kw];
            a2 += sal[2 * 5 + kw] * vb[2 * PW + kw];
            a3 += sal[3 * 5 + kw] * vb[3 * PW + kw];
            a4 += sal[4 * 5 + kw] * vb[4 * PW + kw];
        }
        const float acc = (a0 + a1) + (a2 + a3) + a4;
        out[((size_t)(b * 256 + n * 32 + v) * 32 + (i0 + r)) * 32 + j] =
            s_gw[64 + v] * acc + (s_gb[64 + v] - s_gw[64 + v] * cV2);
        LDS_FENCE();
    }
}

extern "C" void kernel_launch(void* const* d_in, const int* in_sizes, int n_in,
                              void* d_out, int out_size, void* d_ws, size_t ws_size,
                              hipStream_t stream) {
    const float* x      = (const float*)d_in[0];
    const float* conv_w = (const float*)d_in[1];
    const float* conv_b = (const float*)d_in[2];
    const float* gn_w   = (const float*)d_in[3];
    const float* gn_b   = (const float*)d_in[4];
    float* out = (float*)d_out;

    // ws: attn bf16 padded | rowAgg f32
    ushort_t* attn    = (ushort_t*)d_ws;                    // 8,847,360 ushorts
    float*    rowAgg  = (float*)(attn + 8847360);           // 61,440

    conv_gemm<<<dim3(128, 12), 256, 0, stream>>>(conv_w, x, conv_b, attn, rowAgg);
    local_attn<<<1024, 128, 0, stream>>>(attn, rowAgg, gn_w, gn_b, out);
}